// Round 6
// baseline (171.685 us; speedup 1.0000x reference)
//
#include <hip/hip_runtime.h>
#include <math.h>

constexpr int L = 32768;
constexpr int H = 256;
constexpr int P = 256;
constexpr int T = 64;        // scan chunk length
constexpr int NC = L / T;    // 512 chunks
constexpr int N1 = 2 * P;    // 512: X concat width, INTERLEAVED col = 2p+{0:re,1:im}
constexpr int LDEP = 130;    // epilogue LDS row stride (floats)

typedef __attribute__((ext_vector_type(8))) short short8;
typedef __attribute__((ext_vector_type(4))) float f32x4;

// ---------------- bf16 helpers (RNE) ----------------
__device__ __forceinline__ unsigned f2bf(float f) {
  unsigned u = __float_as_uint(f);
  return (u + 0x7FFFu + ((u >> 16) & 1u)) >> 16;
}

__device__ __forceinline__ void gload_lds16(const unsigned short* g, unsigned short* l) {
  __builtin_amdgcn_global_load_lds(
      (const __attribute__((address_space(1))) unsigned int*)(g),
      (__attribute__((address_space(3))) unsigned int*)(l), 16, 0, 0);
}

// Counted-vmcnt barrier: oldest needed gloads landed, deeper prefetches stay
// in flight. lgkmcnt(0) publishes ds_writes / completes ds_reads per wave.
#define KBAR(N) do { \
    asm volatile("s_waitcnt vmcnt(" #N ") lgkmcnt(0)" ::: "memory"); \
    __builtin_amdgcn_s_barrier(); \
    __builtin_amdgcn_sched_barrier(0); \
  } while (0)

// Pin VMEM issue order only (ALU/VALU/SALU/MFMA/DS may cross).
#define VMEM_FENCE() __builtin_amdgcn_sched_barrier(0x38F)

__device__ __forceinline__ void lambda_bar_of(const float* __restrict__ lam,
                                              const float* __restrict__ lstep,
                                              int p, float& lbr, float& lbi) {
  float lr = lam[2 * p], li = lam[2 * p + 1];
  float st = expf(lstep[p]);
  float ea = expf(lr * st);
  lbr = ea * cosf(li * st);
  lbi = ea * sinf(li * st);
}

// complex (ar+i·ai)*(br+i·bi) -> packed bf16 pair (re low, im high)
__device__ __forceinline__ unsigned pkcm(float ar, float ai, float br, float bi) {
  float re = ar * br - ai * bi;
  float im = fmaf(ar, bi, ai * br);
  return f2bf(re) | (f2bf(im) << 16);
}

// ---------------------------------------------------------------------------
// k_prep: Bcat (512 x 256 bf16), Ccat (256 x 512 bf16),
//         powc (T x P float2 interleaved): lambda_bar^(t+1),
//         sigt: sig bf16 in FRAGMENT-MAJOR tile order:
//   sigt[panel][ks][c]*8shorts, panel=row/128, ks=k/32, chunk c in [0,512):
//   c -> row = 64*(c>>8) + 16*((c>>6)&3) + (c&15), kk = 8*((c>>4)&3).
// ---------------------------------------------------------------------------
__global__ __launch_bounds__(256) void k_prep(const float* __restrict__ sig,
                                              const float* __restrict__ lam,
                                              const float* __restrict__ lstep,
                                              const float* __restrict__ Bri,
                                              const float* __restrict__ Cri,
                                              unsigned short* __restrict__ Bcat,
                                              unsigned short* __restrict__ Ccat,
                                              float* __restrict__ powc,
                                              unsigned short* __restrict__ sigt) {
  int idx = blockIdx.x * 256 + threadIdx.x;  // < 1589248
  if (idx < N1 * H) {
    int n = idx >> 8, k = idx & 255;
    int p = n >> 1, comp = n & 1;
    float lr = lam[2 * p], li = lam[2 * p + 1];
    float st = expf(lstep[p]);
    float ea = expf(lr * st);
    float lbr = ea * cosf(li * st), lbi = ea * sinf(li * st);
    float inv = 1.0f / (lr * lr + li * li);
    float nr = lbr - 1.0f;
    float fr = (nr * lr + lbi * li) * inv;
    float fi = (lbi * lr - nr * li) * inv;
    float br = Bri[2 * (p * H + k)], bi = Bri[2 * (p * H + k) + 1];
    float v = (comp == 0) ? (fr * br - fi * bi) : (fr * bi + fi * br);
    Bcat[idx] = (unsigned short)f2bf(v);
  } else if (idx < 2 * N1 * H) {
    int j = idx - N1 * H;
    int h = j >> 9, k2 = j & 511;
    int p = k2 >> 1;
    float v = ((k2 & 1) == 0) ? Cri[2 * (h * P + p)] : -Cri[2 * (h * P + p) + 1];
    Ccat[j] = (unsigned short)f2bf(v);
  } else if (idx < 2 * N1 * H + T * P) {
    int r = idx - 2 * N1 * H;  // < T*P, r = t*256 + p
    int t = r >> 8, p = r & 255;
    float lr = lam[2 * p], li = lam[2 * p + 1];
    float st = expf(lstep[p]);
    float e = (float)(t + 1);
    float er = expf(e * lr * st);
    powc[2 * r] = er * cosf(e * li * st);
    powc[2 * r + 1] = er * sinf(e * li * st);
  } else {
    int C = idx - (2 * N1 * H + T * P);   // < 1048576 (one 16B chunk each)
    int panel = C >> 12;                   // 4096 chunks per 128-row panel
    int ks = (C >> 9) & 7;
    int c = C & 511;
    int row = ((c >> 8) << 6) + (((c >> 6) & 3) << 4) + (c & 15);
    int kk = ((c >> 4) & 3) << 3;
    const float* s = sig + (size_t)(panel * 128 + row) * 256 + ks * 32 + kk;
    float4 a = *(const float4*)(s);
    float4 b = *(const float4*)(s + 4);
    uint4 w;
    w.x = f2bf(a.x) | (f2bf(a.y) << 16);
    w.y = f2bf(a.z) | (f2bf(a.w) << 16);
    w.z = f2bf(b.x) | (f2bf(b.y) << 16);
    w.w = f2bf(b.z) | (f2bf(b.w) << 16);
    *(uint4*)(sigt + (size_t)C * 8) = w;
  }
}

// ---------------------------------------------------------------------------
// GEMM1 fused: 128x128 tile (2 chunks). BOTH operands via global_load_lds,
// fragment-major, conflict-free. A: 3-deep ring; B: 2-deep. LDS = 40 KB.
// Epilogue: LDS dump + in-block scan -> Xl in TILE ORDER (frag-major, so
// gemm2 can global_load_lds it directly) + S transposed [p][NC].
// grid (L/128, N1/128) = (256, 4).
// ---------------------------------------------------------------------------
__global__ __launch_bounds__(256, 4) void k_gemm1s(const unsigned short* __restrict__ sigt,
                                                   const unsigned short* __restrict__ Bcat,
                                                   const float* __restrict__ lam,
                                                   const float* __restrict__ lstep,
                                                   unsigned short* __restrict__ Xl,
                                                   float* __restrict__ Sr,
                                                   float* __restrict__ Si) {
  constexpr int NIT = 8;   // K=256 / 32
  __shared__ __align__(16) char smem[40960];
  unsigned short* sA[3] = {(unsigned short*)smem, (unsigned short*)(smem + 8192),
                           (unsigned short*)(smem + 16384)};
  unsigned short* sB[2] = {(unsigned short*)(smem + 24576), (unsigned short*)(smem + 32768)};
  float* sEpi = (float*)smem;
  const int tid = threadIdx.x;
  const int lane = tid & 63;
  const int wave = tid >> 6;
  const int wc = (wave & 1) * 64;
  const int n0 = blockIdx.y * 128;
  const int brow = ((tid >> 6) << 4) | (tid & 15);    // B staging source row
  const int bko = ((tid >> 4) & 3) * 8;               // B staging k-subgroup
  const int hb = (wave & 1) * 2048;                   // B half base (shorts)
  const int afb = (wave >> 1) * 256;                  // A frag chunk base
  const unsigned short* apan = sigt + (size_t)blockIdx.x * 32768;  // 8 ks * 4096 shorts
  f32x4 acc[4][4];
#pragma unroll
  for (int i = 0; i < 4; i++)
#pragma unroll
    for (int j = 0; j < 4; j++) acc[i][j] = (f32x4){0.f, 0.f, 0.f, 0.f};

#define ISSUE_A1(ks, buf) { \
    gload_lds16(apan + (ks) * 4096 + tid * 8, sA[buf] + tid * 8); \
    gload_lds16(apan + (ks) * 4096 + 2048 + tid * 8, sA[buf] + 2048 + tid * 8); }
#define ISSUE_B1(ks, buf) { \
    gload_lds16(Bcat + (size_t)(n0 + brow) * 256 + (ks) * 32 + bko, sB[buf] + tid * 8); \
    gload_lds16(Bcat + (size_t)(n0 + 64 + brow) * 256 + (ks) * 32 + bko, sB[buf] + 2048 + tid * 8); }

  // prologue: issue A0(2) B0(2) A1(2); wait B0 -> vmcnt(2) leaves A1 in flight
  ISSUE_A1(0, 0);
  VMEM_FENCE();
  ISSUE_B1(0, 0);
  VMEM_FENCE();
  ISSUE_A1(1, 1);
  VMEM_FENCE();
  KBAR(2);
#pragma unroll
  for (int it = 0; it < NIT; it++) {
    if (it + 1 < NIT) ISSUE_B1(it + 1, (it + 1) & 1);
    VMEM_FENCE();
    if (it + 2 < NIT) ISSUE_A1(it + 2, (it + 2) % 3);
    VMEM_FENCE();
    const unsigned short* sAc = sA[it % 3];
    const unsigned short* sBc = sB[it & 1];
    short8 af[4], bfr[4];
#pragma unroll
    for (int i = 0; i < 4; i++) af[i] = *(const short8*)(sAc + (afb + i * 64 + lane) * 8);
#pragma unroll
    for (int j = 0; j < 4; j++) bfr[j] = *(const short8*)(sBc + hb + (j * 64 + lane) * 8);
#pragma unroll
    for (int i = 0; i < 4; i++)
#pragma unroll
      for (int j = 0; j < 4; j++)
        acc[i][j] = __builtin_amdgcn_mfma_f32_16x16x32_bf16(af[i], bfr[j], acc[i][j], 0, 0, 0);
    if (it + 1 < NIT) {
      if (it + 2 < NIT) { KBAR(2); } else { KBAR(0); }
    }
  }
  __syncthreads();

  // ---- epilogue: per chunk-half: dump rows to LDS, scan, store ----
  const int crow = (lane >> 4) * 4, ccol = wc + (lane & 15);
#pragma unroll
  for (int half = 0; half < 2; half++) {
    if ((wave >> 1) == half) {
#pragma unroll
      for (int i = 0; i < 4; i++)
#pragma unroll
        for (int j = 0; j < 4; j++)
#pragma unroll
          for (int g = 0; g < 4; g++)
            sEpi[(crow + i * 16 + g) * LDEP + ccol + j * 16] = acc[i][j][g];
    }
    __syncthreads();
    if (tid < 64) {
      const int pl = tid;
      const int gp = (n0 >> 1) + pl;
      const int c = blockIdx.x * 2 + half;
      float lbr, lbi;
      lambda_bar_of(lam, lstep, gp, lbr, lbi);
      float xr = 0.f, xi = 0.f;
      const float* e = sEpi + 2 * pl;
      // TILE-ORDER Xl destination for global col = n0 + 2*pl, panel blockIdx.x:
      //   ks = col>>5, kkb = (col&31)>>3, in-chunk short offset = col&7
      const int ks = blockIdx.y * 4 + (pl >> 4);
      const int kkb = (pl >> 2) & 3;
      unsigned short* xlb = Xl + (size_t)blockIdx.x * 65536 + ks * 4096 + 2 * (pl & 3);
      for (int tb = 0; tb < T; tb += 8) {
        float2 v[8];
#pragma unroll
        for (int u = 0; u < 8; u++) v[u] = *(const float2*)(e + (tb + u) * LDEP);
        unsigned ov[8];
#pragma unroll
        for (int u = 0; u < 8; u++) {
          float nr = fmaf(lbr, xr, fmaf(-lbi, xi, v[u].x));
          float ni = fmaf(lbr, xi, fmaf(lbi, xr, v[u].y));
          xr = nr; xi = ni;
          ov[u] = f2bf(xr) | (f2bf(xi) << 16);
        }
        const int cb0 = (half << 8) | (((tb >> 4) & 3) << 6) | (kkb << 4) | (tb & 15);
#pragma unroll
        for (int u = 0; u < 8; u++)
          *(unsigned*)(xlb + (cb0 + u) * 8) = ov[u];
      }
      Sr[(size_t)gp * NC + c] = xr;   // TRANSPOSED [p][NC]
      Si[(size_t)gp * NC + c] = xi;
    }
    __syncthreads();
  }
#undef ISSUE_A1
#undef ISSUE_B1
}

// ---------------------------------------------------------------------------
// Parallel carry scan: 256 blocks (one per p) x 64 threads.
// Emits carc: (NC x P float2 interleaved) carry entering each chunk.
// ---------------------------------------------------------------------------
__global__ __launch_bounds__(64) void k_carry2(const float* __restrict__ lam,
                                               const float* __restrict__ lstep,
                                               const float* __restrict__ Sr,
                                               const float* __restrict__ Si,
                                               float* __restrict__ carc) {
  const int p = blockIdx.x;
  const int t = threadIdx.x;  // 0..63
  float lr = lam[2 * p], li = lam[2 * p + 1];
  float st = expf(lstep[p]);
  float eT = expf((float)T * lr * st);
  float lTr = eT * cosf((float)T * li * st);
  float lTi = eT * sinf((float)T * li * st);
  float vr[8], vi[8];
  {
    const float* srp = Sr + (size_t)p * NC + t * 8;
    const float* sip = Si + (size_t)p * NC + t * 8;
    float4 a0 = *(const float4*)(srp), a1 = *(const float4*)(srp + 4);
    float4 b0 = *(const float4*)(sip), b1 = *(const float4*)(sip + 4);
    vr[0] = a0.x; vr[1] = a0.y; vr[2] = a0.z; vr[3] = a0.w;
    vr[4] = a1.x; vr[5] = a1.y; vr[6] = a1.z; vr[7] = a1.w;
    vi[0] = b0.x; vi[1] = b0.y; vi[2] = b0.z; vi[3] = b0.w;
    vi[4] = b1.x; vi[5] = b1.y; vi[6] = b1.z; vi[7] = b1.w;
  }
  float Br = 0.f, Bi = 0.f;
#pragma unroll
  for (int u = 0; u < 8; u++) {
    float nr = fmaf(lTr, Br, fmaf(-lTi, Bi, vr[u]));
    float ni = fmaf(lTr, Bi, fmaf(lTi, Br, vi[u]));
    Br = nr; Bi = ni;
  }
  float e8 = expf(8.0f * (float)T * lr * st);
  float Ar = e8 * cosf(8.0f * (float)T * li * st);
  float Ai = e8 * sinf(8.0f * (float)T * li * st);
#pragma unroll
  for (int d = 1; d < 64; d <<= 1) {
    float Aor = __shfl_up(Ar, d), Aoi = __shfl_up(Ai, d);
    float Bor = __shfl_up(Br, d), Boi = __shfl_up(Bi, d);
    if (t >= d) {
      float nBr = Ar * Bor - Ai * Boi + Br;
      float nBi = Ar * Boi + Ai * Bor + Bi;
      float nAr = Aor * Ar - Aoi * Ai;
      float nAi = Aor * Ai + Aoi * Ar;
      Br = nBr; Bi = nBi; Ar = nAr; Ai = nAi;
    }
  }
  float cr = __shfl_up(Br, 1), ci = __shfl_up(Bi, 1);
  if (t == 0) { cr = 0.f; ci = 0.f; }
#pragma unroll
  for (int u = 0; u < 8; u++) {
    float2 w; w.x = cr; w.y = ci;
    *(float2*)(carc + 2 * ((size_t)(t * 8 + u) * P + p)) = w;
    float nr = fmaf(lTr, cr, fmaf(-lTi, ci, vr[u]));
    float ni = fmaf(lTr, ci, fmaf(lTi, cr, vi[u]));
    cr = nr; ci = ni;
  }
}

// ---------------------------------------------------------------------------
// GEMM2 with fused carry correction as extra K: K=1024 over the SAME Ccat.
//   iters 0..15 : A = Xl (tile-order) via global_load_lds, 3-deep ring,
//                 counted KBAR(2)  [= validated R4-gemm2p loop]
//   iters 16..31: A = pow[t]*carry[c] from L2 tables, reg-staged, ds_write
//                 into the same LDS ring. CONSERVATIVE: single table set,
//                 KBAR(0) every boundary (no vmcnt counting in this phase).
// B (Ccat): 2-deep via global_load_lds. LDS = 32 KB -> 4 blocks/CU.
// Epilogue: + D*sig. grid (L/128, H/64) = (256, 4).
// ---------------------------------------------------------------------------
__global__ __launch_bounds__(256, 4) void k_gemm2c(const unsigned short* __restrict__ Xl,
                                                   const unsigned short* __restrict__ Ccat,
                                                   const float* __restrict__ powc,
                                                   const float* __restrict__ carc,
                                                   const float* __restrict__ sig,
                                                   const float* __restrict__ Dv,
                                                   float* __restrict__ out) {
  constexpr int NIT = 32;   // K=1024 / 32 (two passes over Ccat's K=512)
  __shared__ __align__(16) char smem[32768];
  unsigned short* sA[3] = {(unsigned short*)smem, (unsigned short*)(smem + 8192),
                           (unsigned short*)(smem + 16384)};
  unsigned short* sB[2] = {(unsigned short*)(smem + 24576), (unsigned short*)(smem + 28672)};
  const int tid = threadIdx.x;
  const int lane = tid & 63;
  const int wave = tid >> 6;
  const int m0 = blockIdx.x * 128, n0 = blockIdx.y * 64;
  const int brow = (((tid >> 6) & 3) << 4) | (tid & 15);  // B staging source row (0..63)
  const int bko = ((tid >> 4) & 3) * 8;                   // B staging k-subgroup
  const int afb = (wave >> 1) * 256;                      // A frag chunk base
  const int bfb = (wave & 1) * 2;                         // B frag chunk-group base
  const unsigned short* apan = Xl + (size_t)blockIdx.x * 65536;  // 16 ks * 4096 shorts
  // phase-2 per-thread constants: thread stages chunks {tid, tid+256}:
  //   chunk tid     -> row = t_        (= time within chunk 2*bx),   kk = kk1
  //   chunk tid+256 -> row = t_ + 64   (= time within chunk 2*bx+1), kk = kk1
  const int t_ = (((tid >> 6) & 3) << 4) | (tid & 15);
  const int kk1 = ((tid >> 4) & 3) << 3;
  const float* pwB = powc + t_ * 512 + kk1;                       // + ks*32 floats
  const float* c1B = carc + (size_t)(blockIdx.x * 2) * 512 + kk1;
  const float* c2B = c1B + 512;
  f32x4 acc[4][2];
#pragma unroll
  for (int i = 0; i < 4; i++)
#pragma unroll
    for (int j = 0; j < 2; j++) acc[i][j] = (f32x4){0.f, 0.f, 0.f, 0.f};

#define ISSUE_A2(ks, buf) { \
    gload_lds16(apan + (ks) * 4096 + tid * 8, sA[buf] + tid * 8); \
    gload_lds16(apan + (ks) * 4096 + 2048 + tid * 8, sA[buf] + 2048 + tid * 8); }
#define ISSUE_B2(ks, buf) { \
    gload_lds16(Ccat + (size_t)(n0 + brow) * 512 + (ks) * 32 + bko, sB[buf] + tid * 8); }

  // single table register set (loaded and consumed within one iteration)
  float4 pa, pb, ca, cb, da, db;
#define LOAD_T(ks) { const int ko_ = (ks) * 32; \
    pa = *(const float4*)(pwB + ko_); pb = *(const float4*)(pwB + ko_ + 4); \
    ca = *(const float4*)(c1B + ko_); cb = *(const float4*)(c1B + ko_ + 4); \
    da = *(const float4*)(c2B + ko_); db = *(const float4*)(c2B + ko_ + 4); }
#define STAGE_FIX(buf) { \
    uint4 o1, o2; \
    o1.x = pkcm(pa.x, pa.y, ca.x, ca.y); \
    o1.y = pkcm(pa.z, pa.w, ca.z, ca.w); \
    o1.z = pkcm(pb.x, pb.y, cb.x, cb.y); \
    o1.w = pkcm(pb.z, pb.w, cb.z, cb.w); \
    o2.x = pkcm(pa.x, pa.y, da.x, da.y); \
    o2.y = pkcm(pa.z, pa.w, da.z, da.w); \
    o2.z = pkcm(pb.x, pb.y, db.x, db.y); \
    o2.w = pkcm(pb.z, pb.w, db.z, db.w); \
    unsigned short* dA_ = sA[buf]; \
    *(uint4*)(dA_ + tid * 8) = o1; \
    *(uint4*)(dA_ + 2048 + tid * 8) = o2; }

  // prologue: A0(2) B0(1) A1(2); wait B0 -> vmcnt(2) leaves A1 in flight
  ISSUE_A2(0, 0);
  VMEM_FENCE();
  ISSUE_B2(0, 0);
  VMEM_FENCE();
  ISSUE_A2(1, 1);
  VMEM_FENCE();
  KBAR(2);
#pragma unroll
  for (int it = 0; it < NIT; it++) {
    // phase-2 table loads FIRST (oldest), so STAGE_FIX's implicit wait
    // leaves B(it+1) in flight
    if (it >= 15 && it + 1 < NIT) LOAD_T((it + 1) & 15);
    VMEM_FENCE();
    if (it + 1 < NIT) ISSUE_B2((it + 1) & 15, (it + 1) & 1);
    VMEM_FENCE();
    if (it + 2 < 16) ISSUE_A2(it + 2, (it + 2) % 3);
    VMEM_FENCE();
    if (it >= 15 && it + 1 < NIT) STAGE_FIX((it + 1) % 3);
    const unsigned short* sAc = sA[it % 3];
    const unsigned short* sBc = sB[it & 1];
    short8 af[4], bfr[2];
#pragma unroll
    for (int i = 0; i < 4; i++) af[i] = *(const short8*)(sAc + (afb + i * 64 + lane) * 8);
#pragma unroll
    for (int j = 0; j < 2; j++) bfr[j] = *(const short8*)(sBc + ((bfb + j) * 64 + lane) * 8);
#pragma unroll
    for (int i = 0; i < 4; i++)
#pragma unroll
      for (int j = 0; j < 2; j++)
        acc[i][j] = __builtin_amdgcn_mfma_f32_16x16x32_bf16(af[i], bfr[j], acc[i][j], 0, 0, 0);
    if (it + 1 < NIT) {
      if (it + 2 < 16) { KBAR(2); }   // phase 1: A(it+2) gloads stay in flight
      else { KBAR(0); }               // transition + phase 2: full drain
    }
  }

  const int crow = (wave >> 1) * 64 + (lane >> 4) * 4;
  const int ccol = (wave & 1) * 32 + (lane & 15);
  float dcol[2];
#pragma unroll
  for (int j = 0; j < 2; j++) dcol[j] = Dv[n0 + ccol + j * 16];
#pragma unroll
  for (int i = 0; i < 4; i++)
#pragma unroll
    for (int j = 0; j < 2; j++) {
      int col = n0 + ccol + j * 16;
#pragma unroll
      for (int g = 0; g < 4; g++) {
        int row = m0 + crow + i * 16 + g;
        out[(size_t)row * H + col] = acc[i][j][g] + dcol[j] * sig[(size_t)row * H + col];
      }
    }
#undef ISSUE_A2
#undef ISSUE_B2
#undef LOAD_T
#undef STAGE_FIX
}

// ---------------------------------------------------------------------------
// Launch
// ---------------------------------------------------------------------------
extern "C" void kernel_launch(void* const* d_in, const int* in_sizes, int n_in,
                              void* d_out, int out_size, void* d_ws, size_t ws_size,
                              hipStream_t stream) {
  const float* sig = (const float*)d_in[0];   // (L,H)
  const float* lam = (const float*)d_in[1];   // (P,2)
  const float* Bri = (const float*)d_in[2];   // (P,H,2)
  const float* Cri = (const float*)d_in[3];   // (H,P,2)
  const float* Dv  = (const float*)d_in[4];   // (H,)
  const float* lst = (const float*)d_in[5];   // (P,)
  float* out = (float*)d_out;

  unsigned short* Bcat = (unsigned short*)d_ws;             // N1*H bf16
  unsigned short* Ccat = Bcat + (size_t)N1 * H;             // H*N1 bf16
  unsigned short* Xl   = Ccat + (size_t)H * N1;             // L*N1 bf16 (tile order)
  float* powc = (float*)(Xl + (size_t)L * N1);              // T*P float2
  float* carc = powc + 2 * T * P;                           // NC*P float2
  float* Sr   = carc + 2 * NC * P;                          // P*NC (transposed)
  float* Si   = Sr + NC * P;
  unsigned short* sigt = (unsigned short*)(Si + NC * P);    // L*H bf16, tile order

  k_prep<<<(2 * N1 * H + T * P + L * H / 8) / 256, 256, 0, stream>>>(
      sig, lam, lst, Bri, Cri, Bcat, Ccat, powc, sigt);
  dim3 g1(L / 128, N1 / 128);
  k_gemm1s<<<g1, 256, 0, stream>>>(sigt, Bcat, lam, lst, Xl, Sr, Si);
  k_carry2<<<P, 64, 0, stream>>>(lam, lst, Sr, Si, carc);
  dim3 g2(L / 128, H / 64);
  k_gemm2c<<<g2, 256, 0, stream>>>(Xl, Ccat, powc, carc, sig, Dv, out);
}

// Round 9
// 165.438 us; speedup vs baseline: 1.0378x; 1.0378x over previous
//
#include <hip/hip_runtime.h>
#include <math.h>

constexpr int L = 32768;
constexpr int H = 256;
constexpr int P = 256;
constexpr int T = 64;        // scan chunk length
constexpr int NC = L / T;    // 512 chunks
constexpr int N1 = 2 * P;    // 512: X concat width, INTERLEAVED col = 2p+{0:re,1:im}
constexpr int LDEP = 130;    // epilogue LDS row stride (floats)

typedef __attribute__((ext_vector_type(8))) short short8;
typedef __attribute__((ext_vector_type(4))) float f32x4;

// ---------------- bf16 helpers (RNE) ----------------
__device__ __forceinline__ unsigned f2bf(float f) {
  unsigned u = __float_as_uint(f);
  return (u + 0x7FFFu + ((u >> 16) & 1u)) >> 16;
}
__device__ __forceinline__ float bf_lo(unsigned u) { return __uint_as_float(u << 16); }
__device__ __forceinline__ float bf_hi(unsigned u) { return __uint_as_float(u & 0xFFFF0000u); }

__device__ __forceinline__ void gload_lds16(const unsigned short* g, unsigned short* l) {
  __builtin_amdgcn_global_load_lds(
      (const __attribute__((address_space(1))) unsigned int*)(g),
      (__attribute__((address_space(3))) unsigned int*)(l), 16, 0, 0);
}

// Counted-vmcnt barrier: oldest needed gloads landed, deeper prefetches stay
// in flight. lgkmcnt(0) publishes ds_writes / completes ds_reads per wave.
#define KBAR(N) do { \
    asm volatile("s_waitcnt vmcnt(" #N ") lgkmcnt(0)" ::: "memory"); \
    __builtin_amdgcn_s_barrier(); \
    __builtin_amdgcn_sched_barrier(0); \
  } while (0)

// Pin VMEM issue order only (ALU/VALU/SALU/MFMA/DS may cross).
#define VMEM_FENCE() __builtin_amdgcn_sched_barrier(0x38F)

__device__ __forceinline__ void lambda_bar_of(const float* __restrict__ lam,
                                              const float* __restrict__ lstep,
                                              int p, float& lbr, float& lbi) {
  float lr = lam[2 * p], li = lam[2 * p + 1];
  float st = expf(lstep[p]);
  float ea = expf(lr * st);
  lbr = ea * cosf(li * st);
  lbi = ea * sinf(li * st);
}

// x (packed bf16 pair) + (pr+i·pi)*(cr+i·ci) -> packed bf16 pair  [k_fix math]
__device__ __forceinline__ unsigned mix1(unsigned u, float pr, float pi, float cr, float ci) {
  float re = bf_lo(u) + (pr * cr - pi * ci);
  float im = bf_hi(u) + (pr * ci + pi * cr);
  return f2bf(re) | (f2bf(im) << 16);
}

// ---------------------------------------------------------------------------
// k_prep: Bcat (512 x 256 bf16), Ccat (256 x 512 bf16),
//         powc (T x P float2 interleaved): lambda_bar^(t+1),
//         sigt: sig bf16 in FRAGMENT-MAJOR tile order.      [unchanged]
// ---------------------------------------------------------------------------
__global__ __launch_bounds__(256) void k_prep(const float* __restrict__ sig,
                                              const float* __restrict__ lam,
                                              const float* __restrict__ lstep,
                                              const float* __restrict__ Bri,
                                              const float* __restrict__ Cri,
                                              unsigned short* __restrict__ Bcat,
                                              unsigned short* __restrict__ Ccat,
                                              float* __restrict__ powc,
                                              unsigned short* __restrict__ sigt) {
  int idx = blockIdx.x * 256 + threadIdx.x;  // < 1589248
  if (idx < N1 * H) {
    int n = idx >> 8, k = idx & 255;
    int p = n >> 1, comp = n & 1;
    float lr = lam[2 * p], li = lam[2 * p + 1];
    float st = expf(lstep[p]);
    float ea = expf(lr * st);
    float lbr = ea * cosf(li * st), lbi = ea * sinf(li * st);
    float inv = 1.0f / (lr * lr + li * li);
    float nr = lbr - 1.0f;
    float fr = (nr * lr + lbi * li) * inv;
    float fi = (lbi * lr - nr * li) * inv;
    float br = Bri[2 * (p * H + k)], bi = Bri[2 * (p * H + k) + 1];
    float v = (comp == 0) ? (fr * br - fi * bi) : (fr * bi + fi * br);
    Bcat[idx] = (unsigned short)f2bf(v);
  } else if (idx < 2 * N1 * H) {
    int j = idx - N1 * H;
    int h = j >> 9, k2 = j & 511;
    int p = k2 >> 1;
    float v = ((k2 & 1) == 0) ? Cri[2 * (h * P + p)] : -Cri[2 * (h * P + p) + 1];
    Ccat[j] = (unsigned short)f2bf(v);
  } else if (idx < 2 * N1 * H + T * P) {
    int r = idx - 2 * N1 * H;  // < T*P, r = t*256 + p
    int t = r >> 8, p = r & 255;
    float lr = lam[2 * p], li = lam[2 * p + 1];
    float st = expf(lstep[p]);
    float e = (float)(t + 1);
    float er = expf(e * lr * st);
    powc[2 * r] = er * cosf(e * li * st);
    powc[2 * r + 1] = er * sinf(e * li * st);
  } else {
    int C = idx - (2 * N1 * H + T * P);   // < 1048576 (one 16B chunk each)
    int panel = C >> 12;                   // 4096 chunks per 128-row panel
    int ks = (C >> 9) & 7;
    int c = C & 511;
    int row = ((c >> 8) << 6) + (((c >> 6) & 3) << 4) + (c & 15);
    int kk = ((c >> 4) & 3) << 3;
    const float* s = sig + (size_t)(panel * 128 + row) * 256 + ks * 32 + kk;
    float4 a = *(const float4*)(s);
    float4 b = *(const float4*)(s + 4);
    uint4 w;
    w.x = f2bf(a.x) | (f2bf(a.y) << 16);
    w.y = f2bf(a.z) | (f2bf(a.w) << 16);
    w.z = f2bf(b.x) | (f2bf(b.y) << 16);
    w.w = f2bf(b.z) | (f2bf(b.w) << 16);
    *(uint4*)(sigt + (size_t)C * 8) = w;
  }
}

// ---------------------------------------------------------------------------
// GEMM1 fused: 128x128 tile (2 chunks). BOTH operands via global_load_lds,
// fragment-major, conflict-free. A: 3-deep ring; B: 2-deep. LDS = 40 KB.
// Epilogue: LDS dump + in-block scan -> Xl in TILE ORDER + S [p][NC].
// grid (L/128, N1/128) = (256, 4).                          [unchanged]
// ---------------------------------------------------------------------------
__global__ __launch_bounds__(256, 4) void k_gemm1s(const unsigned short* __restrict__ sigt,
                                                   const unsigned short* __restrict__ Bcat,
                                                   const float* __restrict__ lam,
                                                   const float* __restrict__ lstep,
                                                   unsigned short* __restrict__ Xl,
                                                   float* __restrict__ Sr,
                                                   float* __restrict__ Si) {
  constexpr int NIT = 8;   // K=256 / 32
  __shared__ __align__(16) char smem[40960];
  unsigned short* sA[3] = {(unsigned short*)smem, (unsigned short*)(smem + 8192),
                           (unsigned short*)(smem + 16384)};
  unsigned short* sB[2] = {(unsigned short*)(smem + 24576), (unsigned short*)(smem + 32768)};
  float* sEpi = (float*)smem;
  const int tid = threadIdx.x;
  const int lane = tid & 63;
  const int wave = tid >> 6;
  const int wc = (wave & 1) * 64;
  const int n0 = blockIdx.y * 128;
  const int brow = ((tid >> 6) << 4) | (tid & 15);    // B staging source row
  const int bko = ((tid >> 4) & 3) * 8;               // B staging k-subgroup
  const int hb = (wave & 1) * 2048;                   // B half base (shorts)
  const int afb = (wave >> 1) * 256;                  // A frag chunk base
  const unsigned short* apan = sigt + (size_t)blockIdx.x * 32768;  // 8 ks * 4096 shorts
  f32x4 acc[4][4];
#pragma unroll
  for (int i = 0; i < 4; i++)
#pragma unroll
    for (int j = 0; j < 4; j++) acc[i][j] = (f32x4){0.f, 0.f, 0.f, 0.f};

#define ISSUE_A1(ks, buf) { \
    gload_lds16(apan + (ks) * 4096 + tid * 8, sA[buf] + tid * 8); \
    gload_lds16(apan + (ks) * 4096 + 2048 + tid * 8, sA[buf] + 2048 + tid * 8); }
#define ISSUE_B1(ks, buf) { \
    gload_lds16(Bcat + (size_t)(n0 + brow) * 256 + (ks) * 32 + bko, sB[buf] + tid * 8); \
    gload_lds16(Bcat + (size_t)(n0 + 64 + brow) * 256 + (ks) * 32 + bko, sB[buf] + 2048 + tid * 8); }

  // prologue: issue A0(2) B0(2) A1(2); wait B0 -> vmcnt(2) leaves A1 in flight
  ISSUE_A1(0, 0);
  VMEM_FENCE();
  ISSUE_B1(0, 0);
  VMEM_FENCE();
  ISSUE_A1(1, 1);
  VMEM_FENCE();
  KBAR(2);
#pragma unroll
  for (int it = 0; it < NIT; it++) {
    if (it + 1 < NIT) ISSUE_B1(it + 1, (it + 1) & 1);
    VMEM_FENCE();
    if (it + 2 < NIT) ISSUE_A1(it + 2, (it + 2) % 3);
    VMEM_FENCE();
    const unsigned short* sAc = sA[it % 3];
    const unsigned short* sBc = sB[it & 1];
    short8 af[4], bfr[4];
#pragma unroll
    for (int i = 0; i < 4; i++) af[i] = *(const short8*)(sAc + (afb + i * 64 + lane) * 8);
#pragma unroll
    for (int j = 0; j < 4; j++) bfr[j] = *(const short8*)(sBc + hb + (j * 64 + lane) * 8);
#pragma unroll
    for (int i = 0; i < 4; i++)
#pragma unroll
      for (int j = 0; j < 4; j++)
        acc[i][j] = __builtin_amdgcn_mfma_f32_16x16x32_bf16(af[i], bfr[j], acc[i][j], 0, 0, 0);
    if (it + 1 < NIT) {
      if (it + 2 < NIT) { KBAR(2); } else { KBAR(0); }
    }
  }
  __syncthreads();

  // ---- epilogue: per chunk-half: dump rows to LDS, scan, store ----
  const int crow = (lane >> 4) * 4, ccol = wc + (lane & 15);
#pragma unroll
  for (int half = 0; half < 2; half++) {
    if ((wave >> 1) == half) {
#pragma unroll
      for (int i = 0; i < 4; i++)
#pragma unroll
        for (int j = 0; j < 4; j++)
#pragma unroll
          for (int g = 0; g < 4; g++)
            sEpi[(crow + i * 16 + g) * LDEP + ccol + j * 16] = acc[i][j][g];
    }
    __syncthreads();
    if (tid < 64) {
      const int pl = tid;
      const int gp = (n0 >> 1) + pl;
      const int c = blockIdx.x * 2 + half;
      float lbr, lbi;
      lambda_bar_of(lam, lstep, gp, lbr, lbi);
      float xr = 0.f, xi = 0.f;
      const float* e = sEpi + 2 * pl;
      const int ks = blockIdx.y * 4 + (pl >> 4);
      const int kkb = (pl >> 2) & 3;
      unsigned short* xlb = Xl + (size_t)blockIdx.x * 65536 + ks * 4096 + 2 * (pl & 3);
      for (int tb = 0; tb < T; tb += 8) {
        float2 v[8];
#pragma unroll
        for (int u = 0; u < 8; u++) v[u] = *(const float2*)(e + (tb + u) * LDEP);
        unsigned ov[8];
#pragma unroll
        for (int u = 0; u < 8; u++) {
          float nr = fmaf(lbr, xr, fmaf(-lbi, xi, v[u].x));
          float ni = fmaf(lbr, xi, fmaf(lbi, xr, v[u].y));
          xr = nr; xi = ni;
          ov[u] = f2bf(xr) | (f2bf(xi) << 16);
        }
        const int cb0 = (half << 8) | (((tb >> 4) & 3) << 6) | (kkb << 4) | (tb & 15);
#pragma unroll
        for (int u = 0; u < 8; u++)
          *(unsigned*)(xlb + (cb0 + u) * 8) = ov[u];
      }
      Sr[(size_t)gp * NC + c] = xr;   // TRANSPOSED [p][NC]
      Si[(size_t)gp * NC + c] = xi;
    }
    __syncthreads();
  }
#undef ISSUE_A1
#undef ISSUE_B1
}

// ---------------------------------------------------------------------------
// Parallel carry scan: 256 blocks (one per p) x 64 threads.   [unchanged]
// Emits carc: (NC x P float2 interleaved) carry entering each chunk.
// ---------------------------------------------------------------------------
__global__ __launch_bounds__(64) void k_carry2(const float* __restrict__ lam,
                                               const float* __restrict__ lstep,
                                               const float* __restrict__ Sr,
                                               const float* __restrict__ Si,
                                               float* __restrict__ carc) {
  const int p = blockIdx.x;
  const int t = threadIdx.x;  // 0..63
  float lr = lam[2 * p], li = lam[2 * p + 1];
  float st = expf(lstep[p]);
  float eT = expf((float)T * lr * st);
  float lTr = eT * cosf((float)T * li * st);
  float lTi = eT * sinf((float)T * li * st);
  float vr[8], vi[8];
  {
    const float* srp = Sr + (size_t)p * NC + t * 8;
    const float* sip = Si + (size_t)p * NC + t * 8;
    float4 a0 = *(const float4*)(srp), a1 = *(const float4*)(srp + 4);
    float4 b0 = *(const float4*)(sip), b1 = *(const float4*)(sip + 4);
    vr[0] = a0.x; vr[1] = a0.y; vr[2] = a0.z; vr[3] = a0.w;
    vr[4] = a1.x; vr[5] = a1.y; vr[6] = a1.z; vr[7] = a1.w;
    vi[0] = b0.x; vi[1] = b0.y; vi[2] = b0.z; vi[3] = b0.w;
    vi[4] = b1.x; vi[5] = b1.y; vi[6] = b1.z; vi[7] = b1.w;
  }
  float Br = 0.f, Bi = 0.f;
#pragma unroll
  for (int u = 0; u < 8; u++) {
    float nr = fmaf(lTr, Br, fmaf(-lTi, Bi, vr[u]));
    float ni = fmaf(lTr, Bi, fmaf(lTi, Br, vi[u]));
    Br = nr; Bi = ni;
  }
  float e8 = expf(8.0f * (float)T * lr * st);
  float Ar = e8 * cosf(8.0f * (float)T * li * st);
  float Ai = e8 * sinf(8.0f * (float)T * li * st);
#pragma unroll
  for (int d = 1; d < 64; d <<= 1) {
    float Aor = __shfl_up(Ar, d), Aoi = __shfl_up(Ai, d);
    float Bor = __shfl_up(Br, d), Boi = __shfl_up(Bi, d);
    if (t >= d) {
      float nBr = Ar * Bor - Ai * Boi + Br;
      float nBi = Ar * Boi + Ai * Bor + Bi;
      float nAr = Aor * Ar - Aoi * Ai;
      float nAi = Aor * Ai + Aoi * Ar;
      Br = nBr; Bi = nBi; Ar = nAr; Ai = nAi;
    }
  }
  float cr = __shfl_up(Br, 1), ci = __shfl_up(Bi, 1);
  if (t == 0) { cr = 0.f; ci = 0.f; }
#pragma unroll
  for (int u = 0; u < 8; u++) {
    float2 w; w.x = cr; w.y = ci;
    *(float2*)(carc + 2 * ((size_t)(t * 8 + u) * P + p)) = w;
    float nr = fmaf(lTr, cr, fmaf(-lTi, ci, vr[u]));
    float ni = fmaf(lTr, ci, fmaf(lTi, cr, vi[u]));
    cr = nr; ci = ni;
  }
}

// ---------------------------------------------------------------------------
// gemm2v helpers: plain inline functions (no function-like macro pitfalls).
// ---------------------------------------------------------------------------
struct XTRegs {
  uint4 x0, x1;
  float4 p0, p1, c0, c1, d0, d1;
};

__device__ __forceinline__ void load_xt(const unsigned short* apan, const float* pwB,
                                        const float* c1B, const float* c2B,
                                        int ks, int tid, XTRegs& r) {
  const int ko = ks * 32;
  r.x0 = *(const uint4*)(apan + ks * 4096 + tid * 8);
  r.x1 = *(const uint4*)(apan + ks * 4096 + 2048 + tid * 8);
  r.p0 = *(const float4*)(pwB + ko);  r.p1 = *(const float4*)(pwB + ko + 4);
  r.c0 = *(const float4*)(c1B + ko);  r.c1 = *(const float4*)(c1B + ko + 4);
  r.d0 = *(const float4*)(c2B + ko);  r.d1 = *(const float4*)(c2B + ko + 4);
}

__device__ __forceinline__ void stage_fix(unsigned short* dA, int tid, const XTRegs& r) {
  uint4 o1, o2;
  o1.x = mix1(r.x0.x, r.p0.x, r.p0.y, r.c0.x, r.c0.y);
  o1.y = mix1(r.x0.y, r.p0.z, r.p0.w, r.c0.z, r.c0.w);
  o1.z = mix1(r.x0.z, r.p1.x, r.p1.y, r.c1.x, r.c1.y);
  o1.w = mix1(r.x0.w, r.p1.z, r.p1.w, r.c1.z, r.c1.w);
  o2.x = mix1(r.x1.x, r.p0.x, r.p0.y, r.d0.x, r.d0.y);
  o2.y = mix1(r.x1.y, r.p0.z, r.p0.w, r.d0.z, r.d0.w);
  o2.z = mix1(r.x1.z, r.p1.x, r.p1.y, r.d1.x, r.d1.y);
  o2.w = mix1(r.x1.w, r.p1.z, r.p1.w, r.d1.z, r.d1.w);
  *(uint4*)(dA + tid * 8) = o1;
  *(uint4*)(dA + 2048 + tid * 8) = o2;
}

// ---------------------------------------------------------------------------
// GEMM2 with VALU-fused carry fix: 128x64 tile, K=512, grid (256,4) -> 4/CU.
// B (Ccat): 2-deep via global_load_lds (fragment-major, conflict-free).
// A: reg-staged: per iter each thread loads 2x uint4 (tile-order Xl, its
//    two chunks {tid, tid+256}) + 6x float4 tables (pow shared, carry per
//    chunk; L2-resident), applies mix1 (k_fix arithmetic), ds_writes 2x16B
//    into a 2-deep LDS A ring. Issue order [B(it+1), XT(it+2), STAGE(it+1)]
//    -> STAGE's implicit reg-wait = vmcnt(9), non-draining; KBAR(8) steady.
// LDS = 24 KB. Epilogue: + D*sig.
// ---------------------------------------------------------------------------
__global__ __launch_bounds__(256, 4) void k_gemm2v(const unsigned short* __restrict__ Xl,
                                                   const unsigned short* __restrict__ Ccat,
                                                   const float* __restrict__ powc,
                                                   const float* __restrict__ carc,
                                                   const float* __restrict__ sig,
                                                   const float* __restrict__ Dv,
                                                   float* __restrict__ out) {
  constexpr int NIT = 16;   // K=512 / 32
  __shared__ __align__(16) char smem[24576];
  unsigned short* sA[2] = {(unsigned short*)smem, (unsigned short*)(smem + 8192)};
  unsigned short* sB[2] = {(unsigned short*)(smem + 16384), (unsigned short*)(smem + 20480)};
  const int tid = threadIdx.x;
  const int lane = tid & 63;
  const int wave = tid >> 6;
  const int m0 = blockIdx.x * 128, n0 = blockIdx.y * 64;
  const int brow = (((tid >> 6) & 3) << 4) | (tid & 15);  // B staging source row (0..63)
  const int bko = ((tid >> 4) & 3) * 8;                   // B staging k-subgroup
  const int afb = (wave >> 1) * 256;                      // A frag chunk base
  const int bfb = (wave & 1) * 2;                         // B frag chunk-group base
  const unsigned short* apan = Xl + (size_t)blockIdx.x * 65536;  // 16 ks * 4096 shorts
  // staging thread -> (time-in-chunk, k-subgroup); chunks {tid, tid+256}
  const int t_ = (((tid >> 6) & 3) << 4) | (tid & 15);
  const int kk1 = ((tid >> 4) & 3) << 3;
  const float* pwB = powc + t_ * 512 + kk1;                        // + ks*32
  const float* c1B = carc + (size_t)(blockIdx.x * 2) * 512 + kk1;  // chunk 2bx
  const float* c2B = c1B + 512;                                    // chunk 2bx+1
  f32x4 acc[4][2];
#pragma unroll
  for (int i = 0; i < 4; i++)
#pragma unroll
    for (int j = 0; j < 2; j++) acc[i][j] = (f32x4){0.f, 0.f, 0.f, 0.f};

#define ISSUE_B2(ks, buf) { \
    gload_lds16(Ccat + (size_t)(n0 + brow) * 512 + (ks) * 32 + bko, sB[buf] + tid * 8); }

  XTRegs ra, rb;   // two register sets, parity = target tile & 1

  // prologue: XT0(8) B0(1) XT1(8); STAGE(0) waits XT0 -> vmcnt(9);
  // KBAR(8) retires B0, leaves XT1 in flight.
  load_xt(apan, pwB, c1B, c2B, 0, tid, ra);
  VMEM_FENCE();
  ISSUE_B2(0, 0);
  VMEM_FENCE();
  load_xt(apan, pwB, c1B, c2B, 1, tid, rb);
  VMEM_FENCE();
  stage_fix(sA[0], tid, ra);
  KBAR(8);
#pragma unroll
  for (int it = 0; it < NIT; it++) {
    if (it + 1 < NIT) ISSUE_B2(it + 1, (it + 1) & 1);
    VMEM_FENCE();
    if (it + 2 < NIT) {
      if (((it + 2) & 1) == 0) { load_xt(apan, pwB, c1B, c2B, it + 2, tid, ra); }
      else                     { load_xt(apan, pwB, c1B, c2B, it + 2, tid, rb); }
    }
    VMEM_FENCE();
    if (it + 1 < NIT) {
      if (((it + 1) & 1) == 0) { stage_fix(sA[0], tid, ra); }
      else                     { stage_fix(sA[1], tid, rb); }
    }
    const unsigned short* sAc = sA[it & 1];
    const unsigned short* sBc = sB[it & 1];
    short8 af[4], bfr[2];
#pragma unroll
    for (int i = 0; i < 4; i++) af[i] = *(const short8*)(sAc + (afb + i * 64 + lane) * 8);
#pragma unroll
    for (int j = 0; j < 2; j++) bfr[j] = *(const short8*)(sBc + ((bfb + j) * 64 + lane) * 8);
#pragma unroll
    for (int i = 0; i < 4; i++)
#pragma unroll
      for (int j = 0; j < 2; j++)
        acc[i][j] = __builtin_amdgcn_mfma_f32_16x16x32_bf16(af[i], bfr[j], acc[i][j], 0, 0, 0);
    if (it + 1 < NIT) {
      if (it + 2 < NIT) { KBAR(8); }   // retire B(it+1), leave XT(it+2) 8
      else { KBAR(0); }                // tail: drain B(15)
    }
  }

  const int crow = (wave >> 1) * 64 + (lane >> 4) * 4;
  const int ccol = (wave & 1) * 32 + (lane & 15);
  float dcol[2];
#pragma unroll
  for (int j = 0; j < 2; j++) dcol[j] = Dv[n0 + ccol + j * 16];
#pragma unroll
  for (int i = 0; i < 4; i++)
#pragma unroll
    for (int j = 0; j < 2; j++) {
      int col = n0 + ccol + j * 16;
#pragma unroll
      for (int g = 0; g < 4; g++) {
        int row = m0 + crow + i * 16 + g;
        out[(size_t)row * H + col] = acc[i][j][g] + dcol[j] * sig[(size_t)row * H + col];
      }
    }
#undef ISSUE_B2
}

// ---------------------------------------------------------------------------
// Launch
// ---------------------------------------------------------------------------
extern "C" void kernel_launch(void* const* d_in, const int* in_sizes, int n_in,
                              void* d_out, int out_size, void* d_ws, size_t ws_size,
                              hipStream_t stream) {
  const float* sig = (const float*)d_in[0];   // (L,H)
  const float* lam = (const float*)d_in[1];   // (P,2)
  const float* Bri = (const float*)d_in[2];   // (P,H,2)
  const float* Cri = (const float*)d_in[3];   // (H,P,2)
  const float* Dv  = (const float*)d_in[4];   // (H,)
  const float* lst = (const float*)d_in[5];   // (P,)
  float* out = (float*)d_out;

  unsigned short* Bcat = (unsigned short*)d_ws;             // N1*H bf16
  unsigned short* Ccat = Bcat + (size_t)N1 * H;             // H*N1 bf16
  unsigned short* Xl   = Ccat + (size_t)H * N1;             // L*N1 bf16 (tile order)
  float* powc = (float*)(Xl + (size_t)L * N1);              // T*P float2
  float* carc = powc + 2 * T * P;                           // NC*P float2
  float* Sr   = carc + 2 * NC * P;                          // P*NC (transposed)
  float* Si   = Sr + NC * P;
  unsigned short* sigt = (unsigned short*)(Si + NC * P);    // L*H bf16, tile order

  k_prep<<<(2 * N1 * H + T * P + L * H / 8) / 256, 256, 0, stream>>>(
      sig, lam, lst, Bri, Cri, Bcat, Ccat, powc, sigt);
  dim3 g1(L / 128, N1 / 128);
  k_gemm1s<<<g1, 256, 0, stream>>>(sigt, Bcat, lam, lst, Xl, Sr, Si);
  k_carry2<<<P, 64, 0, stream>>>(lam, lst, Sr, Si, carc);
  dim3 g2(L / 128, H / 64);
  k_gemm2v<<<g2, 256, 0, stream>>>(Xl, Ccat, powc, carc, sig, Dv, out);
}